// Round 7
// baseline (2131.584 us; speedup 1.0000x reference)
//
#include <hip/hip_runtime.h>
#include <hip/hip_bf16.h>
#include <stdint.h>

typedef __attribute__((ext_vector_type(4))) float f32x4;
typedef __attribute__((ext_vector_type(8))) short s16x8;
typedef unsigned short u16;

#define BM 128
#define BN 128
#define BK 32

// round-to-nearest-even f32 -> bf16 (bit pattern)
__device__ __forceinline__ u16 f32_to_bf16(float f) {
    uint32_t u = __float_as_uint(f);
    u = u + 0x7FFFu + ((u >> 16) & 1u);
    return (u16)(u >> 16);
}

// Transpose + convert: out[c*R + r] = bf16(in[r*C + c]).  R, C multiples of 32.
__global__ void stein_transpose_f32_bf16(const float* __restrict__ in,
                                         u16* __restrict__ out, int R, int C) {
    __shared__ float tile[32][33];
    const int tx = threadIdx.x, ty = threadIdx.y;     // 32 x 8
    const int c0 = blockIdx.x * 32, r0 = blockIdx.y * 32;
#pragma unroll
    for (int i = 0; i < 32; i += 8)
        tile[ty + i][tx] = in[(size_t)(r0 + ty + i) * C + (c0 + tx)];
    __syncthreads();
#pragma unroll
    for (int i = 0; i < 32; i += 8)
        out[(size_t)(c0 + ty + i) * R + (r0 + tx)] = f32_to_bf16(tile[tx][ty + i]);
}

// Straight convert f32 -> bf16, 4 elements/thread. n multiple of 4.
__global__ void stein_convert_f32_bf16(const float* __restrict__ in,
                                       u16* __restrict__ out, int n) {
    int i = (blockIdx.x * blockDim.x + threadIdx.x) * 4;
    if (i >= n) return;
    f32x4 v = *(const f32x4*)(in + i);
    uint2 u;
    u.x = (uint32_t)f32_to_bf16(v[0]) | ((uint32_t)f32_to_bf16(v[1]) << 16);
    u.y = (uint32_t)f32_to_bf16(v[2]) | ((uint32_t)f32_to_bf16(v[3]) << 16);
    *(uint2*)(out + i) = u;
}

// Runtime-descriptor GEMM op: C[m,n] = sum_k U[m,k] V[n,k]  (NT, bf16 in).
struct GemmOp {
    const u16* U; const u16* V;
    const float* Add;
    u16* OutB; u16* OutT; float* OutF;
    int K, ldu, ldv;
};

// One prefetch set: 4x16B per thread (U chunk0/1, V chunk0/1). Named structs,
// never indexed -> SROA keeps them in VGPRs. R6's uint4 ring ARRAYS were
// lowered to scratch (VGPR_Count 72, WRITE_SIZE 568 MB of spill traffic) —
// the 4x slowdown was spill bandwidth, not the pipeline design.
struct Stage { uint4 u0, u1, v0, v1; };

// grid (16,16,z) — blockIdx.z selects op0/op1. 128x128x32 tile, 4 waves,
// double-buffered LDS with register-staged depth-2 prefetch:
//   global_load_dwordx4 -> named VGPR sets st0..st3 -> ds_write_b128 -> MFMA.
// Ring invariant: tile t lives in set t&3.
//   iter tk: (a) stage tile tk+1 to LDS buf (tk+1)&1 from set (tk+1)&3
//                [loaded at iter tk-2 -> ~2 iters of vmcnt slack]
//            (b) issue loads of tile tk+3 into set (tk+3)&3
//            (c) MFMA tile tk from LDS buf tk&1; __syncthreads (lgkm only —
//                in-flight global loads cross the barrier freely).
// LDS bank swizzle: physical k-chunk p of row r holds logical chunk
// p ^ ((r>>1)&3); readers use kq = (lane>>4) ^ ((lane>>1)&3).
__global__ __launch_bounds__(256, 2) void stein_gemm_nt2(GemmOp op0, GemmOp op1) {
    const GemmOp op = (blockIdx.z == 0) ? op0 : op1;
    __shared__ alignas(16) short Us[2][BM * BK];
    __shared__ alignas(16) short Vs[2][BN * BK];

    const int t = threadIdx.x;
    const int wave = t >> 6;
    const int lane = t & 63;
    const int bm = blockIdx.x, bn = blockIdx.y;
    const int wm = (wave >> 1) * 64;
    const int wn = (wave & 1) * 64;

    const int lrow = lane >> 2;
    const int lchunk = (lane & 3) ^ ((lane >> 3) & 3);
    const int lkof = lchunk * 8;
    const u16* gU0 = op.U + (size_t)(bm * BM + wave * 16 + lrow) * op.ldu + lkof;
    const u16* gU1 = gU0 + (size_t)64 * op.ldu;
    const u16* gV0 = op.V + (size_t)(bn * BN + wave * 16 + lrow) * op.ldv + lkof;
    const u16* gV1 = gV0 + (size_t)64 * op.ldv;
    const int su0 = (wave * 16) * BK;
    char* wUs[2], *wVs[2];
    wUs[0] = (char*)&Us[0][su0];
    wUs[1] = (char*)&Us[1][su0];
    wVs[0] = (char*)&Vs[0][su0];
    wVs[1] = (char*)&Vs[1][su0];
    const int loff = lane * 16;
    const int c2 = 64 * BK * 2;   // byte offset from chunk0 to chunk1 slot

    f32x4 acc[4][4];
#pragma unroll
    for (int i = 0; i < 4; ++i)
#pragma unroll
        for (int j = 0; j < 4; ++j) acc[i][j] = (f32x4){0.f, 0.f, 0.f, 0.f};

    const int arow = wm + (lane & 15);
    const int brow = wn + (lane & 15);
    const int kq = (lane >> 4) ^ ((lane >> 1) & 3);

    const int T = op.K / BK;                // T%4==0 (K=512 or 2048)

#define LOAD_SET(s_, kk_) do { \
        s_.u0 = *(const uint4*)(gU0 + (kk_)); \
        s_.u1 = *(const uint4*)(gU1 + (kk_)); \
        s_.v0 = *(const uint4*)(gV0 + (kk_)); \
        s_.v1 = *(const uint4*)(gV1 + (kk_)); \
    } while (0)

#define STAGE_SET(s_, b_) do { \
        *(uint4*)(wUs[b_] + loff) = s_.u0; \
        *(uint4*)(wUs[b_] + c2 + loff) = s_.u1; \
        *(uint4*)(wVs[b_] + loff) = s_.v0; \
        *(uint4*)(wVs[b_] + c2 + loff) = s_.v1; \
    } while (0)

#define COMPUTE(b_) do { \
        s16x8 af[4], bfr[4]; \
        _Pragma("unroll") \
        for (int i = 0; i < 4; ++i) \
            af[i] = ((const s16x8*)Us[b_])[(arow + i * 16) * (BK / 8) + kq]; \
        _Pragma("unroll") \
        for (int j = 0; j < 4; ++j) \
            bfr[j] = ((const s16x8*)Vs[b_])[(brow + j * 16) * (BK / 8) + kq]; \
        _Pragma("unroll") \
        for (int i = 0; i < 4; ++i) \
            _Pragma("unroll") \
            for (int j = 0; j < 4; ++j) \
                acc[i][j] = __builtin_amdgcn_mfma_f32_16x16x32_bf16( \
                    af[i], bfr[j], acc[i][j], 0, 0, 0); \
    } while (0)

#define STEP(tk_, b_, sSt_, sLd_) do { \
        if ((tk_) + 1 < T) STAGE_SET(sSt_, (b_) ^ 1); \
        if ((tk_) + 3 < T) LOAD_SET(sLd_, ((tk_) + 3) * BK); \
        COMPUTE(b_); \
        __syncthreads(); \
    } while (0)

    Stage st0, st1, st2, st3;
    // prologue: tiles 0..2 -> sets 0..2; stage tile 0 into buf 0
    LOAD_SET(st0, 0);
    LOAD_SET(st1, BK);
    LOAD_SET(st2, 2 * BK);
    STAGE_SET(st0, 0);
    __syncthreads();

    for (int tg = 0; tg < T; tg += 4) {
        STEP(tg + 0, 0, st1, st3);
        STEP(tg + 1, 1, st2, st0);
        STEP(tg + 2, 0, st3, st1);
        STEP(tg + 3, 1, st0, st2);
    }
#undef LOAD_SET
#undef STAGE_SET
#undef COMPUTE
#undef STEP

    // ---- epilogue ----  C/D layout: col=lane&15, row=(lane>>4)*4+r
    const int ldo = 2048;
    const int ccol = lane & 15;
    const int crow = (lane >> 4) * 4;
#pragma unroll
    for (int i = 0; i < 4; ++i) {
#pragma unroll
        for (int j = 0; j < 4; ++j) {
            const int gr0 = bm * BM + wm + i * 16 + crow;
            const int gc = bn * BN + wn + j * 16 + ccol;
            float v[4];
#pragma unroll
            for (int r = 0; r < 4; ++r) {
                v[r] = acc[i][j][r];
                if (op.Add) v[r] += op.Add[(size_t)(gr0 + r) * ldo + gc];
            }
            if (op.OutB) {
#pragma unroll
                for (int r = 0; r < 4; ++r)
                    op.OutB[(size_t)(gr0 + r) * ldo + gc] = f32_to_bf16(v[r]);
            }
            if (op.OutT) {
                uint2 u;
                u.x = (uint32_t)f32_to_bf16(v[0]) | ((uint32_t)f32_to_bf16(v[1]) << 16);
                u.y = (uint32_t)f32_to_bf16(v[2]) | ((uint32_t)f32_to_bf16(v[3]) << 16);
                *(uint2*)(&op.OutT[(size_t)gc * ldo + gr0]) = u;   // gr0 % 4 == 0
            }
            if (op.OutF) {
#pragma unroll
                for (int r = 0; r < 4; ++r)
                    op.OutF[(size_t)(gr0 + r) * ldo + gc] = v[r];
            }
        }
    }
}

static inline GemmOp mkop(const u16* U, const u16* V, int K, int ldu, int ldv,
                          const float* Add, u16* OutB, u16* OutT, float* OutF) {
    GemmOp o;
    o.U = U; o.V = V; o.Add = Add; o.OutB = OutB; o.OutT = OutT; o.OutF = OutF;
    o.K = K; o.ldu = ldu; o.ldv = ldv;
    return o;
}

extern "C" void kernel_launch(void* const* d_in, const int* in_sizes, int n_in,
                              void* d_out, int out_size, void* d_ws, size_t ws_size,
                              hipStream_t stream) {
    const float* A = (const float*)d_in[0];     // (2048, 2048)
    const float* A_F = (const float*)d_in[1];   // (2048, 2048)
    const float* C = (const float*)d_in[2];     // (512, 2048)
    const float* C_F = (const float*)d_in[3];   // (512, 2048)
    const int n = 2048, p = 512;
    (void)in_sizes; (void)n_in; (void)out_size; (void)ws_size;

    char* ws = (char*)d_ws;
    const size_t MB = 1u << 20;
    // ---- Smith squaring, 6 levels -> S_64 (measured absmax 0.5).
    u16* AT   = (u16*)(ws + 0 * MB);    // A^T  bf16  (A_0 transposed form)
    u16* Ab   = (u16*)(ws + 8 * MB);    // A    bf16  (A_0 row form)
    u16* AFT  = (u16*)(ws + 16 * MB);   // B=A_F^T row bf16 (B_0 row form)
    u16* AFb  = (u16*)(ws + 24 * MB);   // A_F  bf16  (B_0 transposed form)
    u16* CFT  = (u16*)(ws + 32 * MB);   // C_F^T bf16 (2048x512)
    u16* CT   = (u16*)(ws + 34 * MB);   // C^T   bf16 (2048x512)
    float* R32 = (float*)(ws + 36 * MB);// running R fp32
    u16* Rb   = (u16*)(ws + 52 * MB);   // running R bf16 row
    u16* XT   = (u16*)(ws + 60 * MB);   // (R*A_i)^T bf16
    u16* Tb1  = (u16*)(ws + 68 * MB);   // ping-pong set 1: B_i row
    u16* TbT1 = (u16*)(ws + 76 * MB);   //                  B_i^T
    u16* Ub1  = (u16*)(ws + 84 * MB);   //                  A_i row
    u16* UbT1 = (u16*)(ws + 92 * MB);   //                  A_i^T

    dim3 tb(32, 8);
    stein_transpose_f32_bf16<<<dim3(64, 64), tb, 0, stream>>>(A, AT, n, n);
    stein_convert_f32_bf16<<<4096, 256, 0, stream>>>(A, Ab, n * n);
    stein_transpose_f32_bf16<<<dim3(64, 64), tb, 0, stream>>>(A_F, AFT, n, n);
    stein_convert_f32_bf16<<<4096, 256, 0, stream>>>(A_F, AFb, n * n);
    stein_transpose_f32_bf16<<<dim3(64, 16), tb, 0, stream>>>(C_F, CFT, p, n);
    stein_transpose_f32_bf16<<<dim3(64, 16), tb, 0, stream>>>(C, CT, p, n);

    dim3 blk(256);
    // R_0 = C_F^T C  (fp32 + bf16 row)
    {
        GemmOp r0 = mkop(CFT, CT, p, p, p, nullptr, Rb, nullptr, R32);
        stein_gemm_nt2<<<dim3(16, 16, 1), blk, 0, stream>>>(r0, r0);
    }

    u16* Tb[2]  = {AFT, Tb1};
    u16* TbT[2] = {AFb, TbT1};
    u16* Ub[2]  = {Ab, Ub1};
    u16* UbT[2] = {AT, UbT1};

    for (int i = 0; i < 6; ++i) {
        const int c = i & 1, nx = c ^ 1;
        GemmOp oXT = mkop(Rb, UbT[c], n, n, n, nullptr, nullptr, XT, nullptr);
        if (i < 5) {
            GemmOp oBsq = mkop(Tb[c], TbT[c], n, n, n, nullptr, Tb[nx], TbT[nx], nullptr);
            stein_gemm_nt2<<<dim3(16, 16, 2), blk, 0, stream>>>(oXT, oBsq);
            GemmOp oRup = mkop(Tb[c], XT, n, n, n, R32, Rb, nullptr, R32);
            GemmOp oAsq = mkop(Ub[c], UbT[c], n, n, n, nullptr, Ub[nx], UbT[nx], nullptr);
            stein_gemm_nt2<<<dim3(16, 16, 2), blk, 0, stream>>>(oRup, oAsq);
        } else {
            stein_gemm_nt2<<<dim3(16, 16, 1), blk, 0, stream>>>(oXT, oXT);
            // final: S_64 = B_5 X + R -> fp32 d_out
            GemmOp oFin = mkop(Tb[c], XT, n, n, n, R32, nullptr, nullptr, (float*)d_out);
            stein_gemm_nt2<<<dim3(16, 16, 1), blk, 0, stream>>>(oFin, oFin);
        }
    }
}

// Round 8
// 823.746 us; speedup vs baseline: 2.5877x; 2.5877x over previous
//
#include <hip/hip_runtime.h>
#include <hip/hip_bf16.h>
#include <stdint.h>

typedef __attribute__((ext_vector_type(4))) float f32x4;
typedef __attribute__((ext_vector_type(8))) short s16x8;
typedef unsigned short u16;

#define BM 64
#define BN 128
#define BK 32

// round-to-nearest-even f32 -> bf16 (bit pattern)
__device__ __forceinline__ u16 f32_to_bf16(float f) {
    uint32_t u = __float_as_uint(f);
    u = u + 0x7FFFu + ((u >> 16) & 1u);
    return (u16)(u >> 16);
}

__device__ __forceinline__ void gld_lds16(const void* g, void* l) {
    __builtin_amdgcn_global_load_lds(
        (const __attribute__((address_space(1))) uint32_t*)g,
        (__attribute__((address_space(3))) uint32_t*)l,
        16, 0, 0);
}

// Transpose + convert: out[c*R + r] = bf16(in[r*C + c]).  R, C multiples of 32.
__global__ void stein_transpose_f32_bf16(const float* __restrict__ in,
                                         u16* __restrict__ out, int R, int C) {
    __shared__ float tile[32][33];
    const int tx = threadIdx.x, ty = threadIdx.y;     // 32 x 8
    const int c0 = blockIdx.x * 32, r0 = blockIdx.y * 32;
#pragma unroll
    for (int i = 0; i < 32; i += 8)
        tile[ty + i][tx] = in[(size_t)(r0 + ty + i) * C + (c0 + tx)];
    __syncthreads();
#pragma unroll
    for (int i = 0; i < 32; i += 8)
        out[(size_t)(c0 + ty + i) * R + (r0 + tx)] = f32_to_bf16(tile[tx][ty + i]);
}

// Straight convert f32 -> bf16, 4 elements/thread. n multiple of 4.
__global__ void stein_convert_f32_bf16(const float* __restrict__ in,
                                       u16* __restrict__ out, int n) {
    int i = (blockIdx.x * blockDim.x + threadIdx.x) * 4;
    if (i >= n) return;
    f32x4 v = *(const f32x4*)(in + i);
    uint2 u;
    u.x = (uint32_t)f32_to_bf16(v[0]) | ((uint32_t)f32_to_bf16(v[1]) << 16);
    u.y = (uint32_t)f32_to_bf16(v[2]) | ((uint32_t)f32_to_bf16(v[3]) << 16);
    *(uint2*)(out + i) = u;
}

// Runtime-descriptor GEMM op: C[m,n] = sum_k U[m,k] V[n,k]  (NT, bf16 in).
struct GemmOp {
    const u16* U; const u16* V;
    const float* Add;
    u16* OutB; u16* OutT; float* OutF;
    int K, ldu, ldv;
};

// grid (32,16,z) — blockIdx.z selects op0/op1. 64x128x32 tile, 4 waves
// (each 32x64: wm=(wave>>1)*32, wn=(wave&1)*64, 2x4 16x16 accs).
// R8 rationale: R4's 128x128 @ 2 blocks/CU showed MfmaUtil 19 / VALU 14 /
// HBM 23% — pure latency bound at 8 waves/CU. Halving BM doubles blocks:
// paired z=2 = 1024 blocks = 4 blocks/CU (16 waves/CU), LDS 24 KB x4 = 96 KB,
// ~50 VGPR + 32 AGPR under the __launch_bounds__(256,4) cap (no spill).
// R5-R7 lesson: cross-barrier register prefetch is compiler-defeated (scratch
// spill, WRITE_SIZE 568 MB) — stay with global_load_lds depth-1 overlap.
// LDS bank swizzle (R4, measured 0 conflicts): physical k-chunk p of row r
// holds logical chunk p ^ ((r>>1)&3); readers use kq=(lane>>4)^((lane>>1)&3).
__global__ __launch_bounds__(256, 4) void stein_gemm_nt2(GemmOp op0, GemmOp op1) {
    const GemmOp op = (blockIdx.z == 0) ? op0 : op1;
    __shared__ alignas(16) short Us[2][BM * BK];   // 2 x 4 KB
    __shared__ alignas(16) short Vs[2][BN * BK];   // 2 x 8 KB

    const int t = threadIdx.x;
    const int wave = t >> 6;
    const int lane = t & 63;
    const int bm = blockIdx.x, bn = blockIdx.y;
    const int wm = (wave >> 1) * 32;
    const int wn = (wave & 1) * 64;

    // staging: wave w stages U rows [16w,16w+16); V rows [16w,16w+16) and +64.
    // lane l -> LDS slot (row = 16w + (l>>2), phys chunk l&3); source logical
    // chunk (l&3) ^ ((l>>3)&3)  [= (row>>1)&3 since row%16 = l>>2].
    const int lrow = lane >> 2;
    const int lchunk = (lane & 3) ^ ((lane >> 3) & 3);
    const int lkof = lchunk * 8;
    const u16* gU0 = op.U + (size_t)(bm * BM + wave * 16 + lrow) * op.ldu + lkof;
    const u16* gV0 = op.V + (size_t)(bn * BN + wave * 16 + lrow) * op.ldv + lkof;
    const u16* gV1 = gV0 + (size_t)64 * op.ldv;
    short* sU = &Us[0][(wave * 16) * BK];          // (+ buffer offset below)
    short* sV0 = &Vs[0][(wave * 16) * BK];
    short* sV1 = &Vs[0][(wave * 16 + 64) * BK];
    const int bufU = BM * BK;                      // elements per U buffer
    const int bufV = BN * BK;

    f32x4 acc[2][4];
#pragma unroll
    for (int i = 0; i < 2; ++i)
#pragma unroll
        for (int j = 0; j < 4; ++j) acc[i][j] = (f32x4){0.f, 0.f, 0.f, 0.f};

    const int arow = wm + (lane & 15);
    const int brow = wn + (lane & 15);
    const int kq = (lane >> 4) ^ ((lane >> 1) & 3);

    // prologue: stage tile 0 into buffer 0
    gld_lds16(gU0, sU);
    gld_lds16(gV0, sV0);
    gld_lds16(gV1, sV1);

    int buf = 0;
    for (int kk = 0; kk < op.K; kk += BK) {
        __syncthreads();   // buffer `buf` staged; prior reads of buf^1 done
        if (kk + BK < op.K) {
            const int kn = kk + BK;
            const int bo = (buf ^ 1);
            gld_lds16(gU0 + kn, sU + bo * bufU);
            gld_lds16(gV0 + kn, sV0 + bo * bufV);
            gld_lds16(gV1 + kn, sV1 + bo * bufV);
        }
        s16x8 af[2], bfr[4];
#pragma unroll
        for (int i = 0; i < 2; ++i)
            af[i] = ((const s16x8*)Us[buf])[(arow + i * 16) * (BK / 8) + kq];
#pragma unroll
        for (int j = 0; j < 4; ++j)
            bfr[j] = ((const s16x8*)Vs[buf])[(brow + j * 16) * (BK / 8) + kq];
#pragma unroll
        for (int i = 0; i < 2; ++i)
#pragma unroll
            for (int j = 0; j < 4; ++j)
                acc[i][j] = __builtin_amdgcn_mfma_f32_16x16x32_bf16(af[i], bfr[j],
                                                                    acc[i][j], 0, 0, 0);
        buf ^= 1;
    }

    // ---- epilogue ----  C/D layout: col=lane&15, row=(lane>>4)*4+r
    const int ldo = 2048;
    const int ccol = lane & 15;
    const int crow = (lane >> 4) * 4;
#pragma unroll
    for (int i = 0; i < 2; ++i) {
#pragma unroll
        for (int j = 0; j < 4; ++j) {
            const int gr0 = bm * BM + wm + i * 16 + crow;
            const int gc = bn * BN + wn + j * 16 + ccol;
            float v[4];
#pragma unroll
            for (int r = 0; r < 4; ++r) {
                v[r] = acc[i][j][r];
                if (op.Add) v[r] += op.Add[(size_t)(gr0 + r) * ldo + gc];
            }
            if (op.OutB) {
#pragma unroll
                for (int r = 0; r < 4; ++r)
                    op.OutB[(size_t)(gr0 + r) * ldo + gc] = f32_to_bf16(v[r]);
            }
            if (op.OutT) {
                uint2 u;
                u.x = (uint32_t)f32_to_bf16(v[0]) | ((uint32_t)f32_to_bf16(v[1]) << 16);
                u.y = (uint32_t)f32_to_bf16(v[2]) | ((uint32_t)f32_to_bf16(v[3]) << 16);
                *(uint2*)(&op.OutT[(size_t)gc * ldo + gr0]) = u;   // gr0 % 4 == 0
            }
            if (op.OutF) {
#pragma unroll
                for (int r = 0; r < 4; ++r)
                    op.OutF[(size_t)(gr0 + r) * ldo + gc] = v[r];
            }
        }
    }
}

static inline GemmOp mkop(const u16* U, const u16* V, int K, int ldu, int ldv,
                          const float* Add, u16* OutB, u16* OutT, float* OutF) {
    GemmOp o;
    o.U = U; o.V = V; o.Add = Add; o.OutB = OutB; o.OutT = OutT; o.OutF = OutF;
    o.K = K; o.ldu = ldu; o.ldv = ldv;
    return o;
}

extern "C" void kernel_launch(void* const* d_in, const int* in_sizes, int n_in,
                              void* d_out, int out_size, void* d_ws, size_t ws_size,
                              hipStream_t stream) {
    const float* A = (const float*)d_in[0];     // (2048, 2048)
    const float* A_F = (const float*)d_in[1];   // (2048, 2048)
    const float* C = (const float*)d_in[2];     // (512, 2048)
    const float* C_F = (const float*)d_in[3];   // (512, 2048)
    const int n = 2048, p = 512;
    (void)in_sizes; (void)n_in; (void)out_size; (void)ws_size;

    char* ws = (char*)d_ws;
    const size_t MB = 1u << 20;
    // ---- Smith squaring, 6 levels -> S_64 (measured absmax 0.5).
    u16* AT   = (u16*)(ws + 0 * MB);    // A^T  bf16  (A_0 transposed form)
    u16* Ab   = (u16*)(ws + 8 * MB);    // A    bf16  (A_0 row form)
    u16* AFT  = (u16*)(ws + 16 * MB);   // B=A_F^T row bf16 (B_0 row form)
    u16* AFb  = (u16*)(ws + 24 * MB);   // A_F  bf16  (B_0 transposed form)
    u16* CFT  = (u16*)(ws + 32 * MB);   // C_F^T bf16 (2048x512)
    u16* CT   = (u16*)(ws + 34 * MB);   // C^T   bf16 (2048x512)
    float* R32 = (float*)(ws + 36 * MB);// running R fp32
    u16* Rb   = (u16*)(ws + 52 * MB);   // running R bf16 row
    u16* XT   = (u16*)(ws + 60 * MB);   // (R*A_i)^T bf16
    u16* Tb1  = (u16*)(ws + 68 * MB);   // ping-pong set 1: B_i row
    u16* TbT1 = (u16*)(ws + 76 * MB);   //                  B_i^T
    u16* Ub1  = (u16*)(ws + 84 * MB);   //                  A_i row
    u16* UbT1 = (u16*)(ws + 92 * MB);   //                  A_i^T

    dim3 tb(32, 8);
    stein_transpose_f32_bf16<<<dim3(64, 64), tb, 0, stream>>>(A, AT, n, n);
    stein_convert_f32_bf16<<<4096, 256, 0, stream>>>(A, Ab, n * n);
    stein_transpose_f32_bf16<<<dim3(64, 64), tb, 0, stream>>>(A_F, AFT, n, n);
    stein_convert_f32_bf16<<<4096, 256, 0, stream>>>(A_F, AFb, n * n);
    stein_transpose_f32_bf16<<<dim3(64, 16), tb, 0, stream>>>(C_F, CFT, p, n);
    stein_transpose_f32_bf16<<<dim3(64, 16), tb, 0, stream>>>(C, CT, p, n);

    dim3 blk(256);
    dim3 g1(32, 16, 1), g2(32, 16, 2);
    // R_0 = C_F^T C  (fp32 + bf16 row)
    {
        GemmOp r0 = mkop(CFT, CT, p, p, p, nullptr, Rb, nullptr, R32);
        stein_gemm_nt2<<<g1, blk, 0, stream>>>(r0, r0);
    }

    u16* Tb[2]  = {AFT, Tb1};
    u16* TbT[2] = {AFb, TbT1};
    u16* Ub[2]  = {Ab, Ub1};
    u16* UbT[2] = {AT, UbT1};

    for (int i = 0; i < 6; ++i) {
        const int c = i & 1, nx = c ^ 1;
        GemmOp oXT = mkop(Rb, UbT[c], n, n, n, nullptr, nullptr, XT, nullptr);
        if (i < 5) {
            GemmOp oBsq = mkop(Tb[c], TbT[c], n, n, n, nullptr, Tb[nx], TbT[nx], nullptr);
            stein_gemm_nt2<<<g2, blk, 0, stream>>>(oXT, oBsq);
            GemmOp oRup = mkop(Tb[c], XT, n, n, n, R32, Rb, nullptr, R32);
            GemmOp oAsq = mkop(Ub[c], UbT[c], n, n, n, nullptr, Ub[nx], UbT[nx], nullptr);
            stein_gemm_nt2<<<g2, blk, 0, stream>>>(oRup, oAsq);
        } else {
            stein_gemm_nt2<<<g1, blk, 0, stream>>>(oXT, oXT);
            // final: S_64 = B_5 X + R -> fp32 d_out
            GemmOp oFin = mkop(Tb[c], XT, n, n, n, R32, nullptr, nullptr, (float*)d_out);
            stein_gemm_nt2<<<g1, blk, 0, stream>>>(oFin, oFin);
        }
    }
}

// Round 9
// 662.007 us; speedup vs baseline: 3.2199x; 1.2443x over previous
//
#include <hip/hip_runtime.h>
#include <hip/hip_bf16.h>
#include <stdint.h>

typedef __attribute__((ext_vector_type(4))) float f32x4;
typedef __attribute__((ext_vector_type(8))) short s16x8;
typedef unsigned short u16;

#define BM 128
#define BN 128
#define BK 64

// round-to-nearest-even f32 -> bf16 (bit pattern)
__device__ __forceinline__ u16 f32_to_bf16(float f) {
    uint32_t u = __float_as_uint(f);
    u = u + 0x7FFFu + ((u >> 16) & 1u);
    return (u16)(u >> 16);
}

__device__ __forceinline__ void gld_lds16(const void* g, void* l) {
    __builtin_amdgcn_global_load_lds(
        (const __attribute__((address_space(1))) uint32_t*)g,
        (__attribute__((address_space(3))) uint32_t*)l,
        16, 0, 0);
}

// Transpose + convert: out[c*R + r] = bf16(in[r*C + c]).  R, C multiples of 32.
__global__ void stein_transpose_f32_bf16(const float* __restrict__ in,
                                         u16* __restrict__ out, int R, int C) {
    __shared__ float tile[32][33];
    const int tx = threadIdx.x, ty = threadIdx.y;     // 32 x 8
    const int c0 = blockIdx.x * 32, r0 = blockIdx.y * 32;
#pragma unroll
    for (int i = 0; i < 32; i += 8)
        tile[ty + i][tx] = in[(size_t)(r0 + ty + i) * C + (c0 + tx)];
    __syncthreads();
#pragma unroll
    for (int i = 0; i < 32; i += 8)
        out[(size_t)(c0 + ty + i) * R + (r0 + tx)] = f32_to_bf16(tile[tx][ty + i]);
}

// Straight convert f32 -> bf16, 4 elements/thread. n multiple of 4.
__global__ void stein_convert_f32_bf16(const float* __restrict__ in,
                                       u16* __restrict__ out, int n) {
    int i = (blockIdx.x * blockDim.x + threadIdx.x) * 4;
    if (i >= n) return;
    f32x4 v = *(const f32x4*)(in + i);
    uint2 u;
    u.x = (uint32_t)f32_to_bf16(v[0]) | ((uint32_t)f32_to_bf16(v[1]) << 16);
    u.y = (uint32_t)f32_to_bf16(v[2]) | ((uint32_t)f32_to_bf16(v[3]) << 16);
    *(uint2*)(out + i) = u;
}

// Runtime-descriptor GEMM op: C[m,n] = sum_k U[m,k] V[n,k]  (NT, bf16 in).
struct GemmOp {
    const u16* U; const u16* V;
    const float* Add;
    u16* OutB; u16* OutT; float* OutF;
    int K, ldu, ldv;
};

// grid (16,16,z) — blockIdx.z selects op0/op1. 128x128x64 tile, 4 waves,
// depth-1 double-buffered LDS via global_load_lds.
// R9 rationale: R4 (BK=32, 2 blk/CU) = 70 µs paired; R8 (64x128, 4 blk/CU)
// = 80 µs — occupancy doesn't help, per-barrier overhead per unit work does.
// BK=64 halves iterations (32 vs 64): 32 MFMA per iter (~2x compute) covers
// the load latency before each barrier drain, half as many drains. LDS
// 64 KB/block -> still 2 blocks/CU (no m132-style occupancy cliff).
// Bank swizzle for 8-chunk rows (row = 128 B, all rows start at bank 0):
// physical chunk p of row r holds logical chunk p ^ (r&7).
//   staging: lane l -> row base+(l>>3), phys chunk l&7, source logical
//            (l&7)^(l>>3); DMA dest = base + lane*16 (wave-uniform rule).
//   reading: row = wm|wn + i*16 + (lane&15)  (row&7 == lane&7), logical
//            chunk s*4+(lane>>4) -> phys (s*4+(lane>>4))^(lane&7).
// Quarter-wave b128 reads: 8 distinct 4-bank groups x 2 lanes = 2-way (free).
__global__ __launch_bounds__(256, 2) void stein_gemm_nt2(GemmOp op0, GemmOp op1) {
    const GemmOp op = (blockIdx.z == 0) ? op0 : op1;
    __shared__ alignas(16) short Us[2][BM * BK];   // 2 x 16 KB
    __shared__ alignas(16) short Vs[2][BN * BK];   // 2 x 16 KB

    const int t = threadIdx.x;
    const int wave = t >> 6;
    const int lane = t & 63;
    const int bm = blockIdx.x, bn = blockIdx.y;
    const int wm = (wave >> 1) * 64;
    const int wn = (wave & 1) * 64;

    // staging: wave w covers rows [32w, 32w+32) of U and V; 4 DMA ops each
    // (8 rows x 128 B per op).
    const int lrow8 = lane >> 3;                  // 0..7
    const int lchunk = (lane & 7) ^ lrow8;        // swizzled source chunk
    const u16* gU = op.U + (size_t)(bm * BM + wave * 32 + lrow8) * op.ldu + lchunk * 8;
    const u16* gV = op.V + (size_t)(bn * BN + wave * 32 + lrow8) * op.ldv + lchunk * 8;
    short* sU = &Us[0][(wave * 32) * BK];
    short* sV = &Vs[0][(wave * 32) * BK];
    const int bufU = BM * BK;                     // elements per buffer
    const int bufV = BN * BK;

    f32x4 acc[4][4];
#pragma unroll
    for (int i = 0; i < 4; ++i)
#pragma unroll
        for (int j = 0; j < 4; ++j) acc[i][j] = (f32x4){0.f, 0.f, 0.f, 0.f};

    const int arow = wm + (lane & 15);
    const int brow = wn + (lane & 15);

    // prologue: stage tile 0 into buffer 0
#pragma unroll
    for (int j = 0; j < 4; ++j) {
        gld_lds16(gU + (size_t)(8 * j) * op.ldu, sU + j * 512);
        gld_lds16(gV + (size_t)(8 * j) * op.ldv, sV + j * 512);
    }

    int buf = 0;
    for (int kk = 0; kk < op.K; kk += BK) {
        __syncthreads();   // buffer `buf` staged; prior reads of buf^1 done
        if (kk + BK < op.K) {
            const int kn = kk + BK;
            const int bo = buf ^ 1;
#pragma unroll
            for (int j = 0; j < 4; ++j) {
                gld_lds16(gU + (size_t)(8 * j) * op.ldu + kn, sU + bo * bufU + j * 512);
                gld_lds16(gV + (size_t)(8 * j) * op.ldv + kn, sV + bo * bufV + j * 512);
            }
        }
#pragma unroll
        for (int s = 0; s < 2; ++s) {
            const int cx = (s * 4 + (lane >> 4)) ^ (lane & 7);   // phys chunk
            s16x8 af[4], bfr[4];
#pragma unroll
            for (int i = 0; i < 4; ++i)
                af[i] = ((const s16x8*)Us[buf])[(arow + i * 16) * (BK / 8) + cx];
#pragma unroll
            for (int j = 0; j < 4; ++j)
                bfr[j] = ((const s16x8*)Vs[buf])[(brow + j * 16) * (BK / 8) + cx];
#pragma unroll
            for (int i = 0; i < 4; ++i)
#pragma unroll
                for (int j = 0; j < 4; ++j)
                    acc[i][j] = __builtin_amdgcn_mfma_f32_16x16x32_bf16(
                        af[i], bfr[j], acc[i][j], 0, 0, 0);
        }
        buf ^= 1;
    }

    // ---- epilogue ----  C/D layout: col=lane&15, row=(lane>>4)*4+r
    const int ldo = 2048;
    const int ccol = lane & 15;
    const int crow = (lane >> 4) * 4;
#pragma unroll
    for (int i = 0; i < 4; ++i) {
#pragma unroll
        for (int j = 0; j < 4; ++j) {
            const int gr0 = bm * BM + wm + i * 16 + crow;
            const int gc = bn * BN + wn + j * 16 + ccol;
            float v[4];
#pragma unroll
            for (int r = 0; r < 4; ++r) {
                v[r] = acc[i][j][r];
                if (op.Add) v[r] += op.Add[(size_t)(gr0 + r) * ldo + gc];
            }
            if (op.OutB) {
#pragma unroll
                for (int r = 0; r < 4; ++r)
                    op.OutB[(size_t)(gr0 + r) * ldo + gc] = f32_to_bf16(v[r]);
            }
            if (op.OutT) {
                uint2 u;
                u.x = (uint32_t)f32_to_bf16(v[0]) | ((uint32_t)f32_to_bf16(v[1]) << 16);
                u.y = (uint32_t)f32_to_bf16(v[2]) | ((uint32_t)f32_to_bf16(v[3]) << 16);
                *(uint2*)(&op.OutT[(size_t)gc * ldo + gr0]) = u;   // gr0 % 4 == 0
            }
            if (op.OutF) {
#pragma unroll
                for (int r = 0; r < 4; ++r)
                    op.OutF[(size_t)(gr0 + r) * ldo + gc] = v[r];
            }
        }
    }
}

static inline GemmOp mkop(const u16* U, const u16* V, int K, int ldu, int ldv,
                          const float* Add, u16* OutB, u16* OutT, float* OutF) {
    GemmOp o;
    o.U = U; o.V = V; o.Add = Add; o.OutB = OutB; o.OutT = OutT; o.OutF = OutF;
    o.K = K; o.ldu = ldu; o.ldv = ldv;
    return o;
}

extern "C" void kernel_launch(void* const* d_in, const int* in_sizes, int n_in,
                              void* d_out, int out_size, void* d_ws, size_t ws_size,
                              hipStream_t stream) {
    const float* A = (const float*)d_in[0];     // (2048, 2048)
    const float* A_F = (const float*)d_in[1];   // (2048, 2048)
    const float* C = (const float*)d_in[2];     // (512, 2048)
    const float* C_F = (const float*)d_in[3];   // (512, 2048)
    const int n = 2048, p = 512;
    (void)in_sizes; (void)n_in; (void)out_size; (void)ws_size;

    char* ws = (char*)d_ws;
    const size_t MB = 1u << 20;
    // ---- Smith squaring, 6 levels -> S_64 (measured absmax 0.5).
    u16* AT   = (u16*)(ws + 0 * MB);    // A^T  bf16  (A_0 transposed form)
    u16* Ab   = (u16*)(ws + 8 * MB);    // A    bf16  (A_0 row form)
    u16* AFT  = (u16*)(ws + 16 * MB);   // B=A_F^T row bf16 (B_0 row form)
    u16* AFb  = (u16*)(ws + 24 * MB);   // A_F  bf16  (B_0 transposed form)
    u16* CFT  = (u16*)(ws + 32 * MB);   // C_F^T bf16 (2048x512)
    u16* CT   = (u16*)(ws + 34 * MB);   // C^T   bf16 (2048x512)
    float* R32 = (float*)(ws + 36 * MB);// running R fp32
    u16* Rb   = (u16*)(ws + 52 * MB);   // running R bf16 row
    u16* XT   = (u16*)(ws + 60 * MB);   // (R*A_i)^T bf16
    u16* Tb1  = (u16*)(ws + 68 * MB);   // ping-pong set 1: B_i row
    u16* TbT1 = (u16*)(ws + 76 * MB);   //                  B_i^T
    u16* Ub1  = (u16*)(ws + 84 * MB);   //                  A_i row
    u16* UbT1 = (u16*)(ws + 92 * MB);   //                  A_i^T

    dim3 tb(32, 8);
    stein_transpose_f32_bf16<<<dim3(64, 64), tb, 0, stream>>>(A, AT, n, n);
    stein_convert_f32_bf16<<<4096, 256, 0, stream>>>(A, Ab, n * n);
    stein_transpose_f32_bf16<<<dim3(64, 64), tb, 0, stream>>>(A_F, AFT, n, n);
    stein_convert_f32_bf16<<<4096, 256, 0, stream>>>(A_F, AFb, n * n);
    stein_transpose_f32_bf16<<<dim3(64, 16), tb, 0, stream>>>(C_F, CFT, p, n);
    stein_transpose_f32_bf16<<<dim3(64, 16), tb, 0, stream>>>(C, CT, p, n);

    dim3 blk(256);
    dim3 g1(16, 16, 1), g2(16, 16, 2);
    // R_0 = C_F^T C  (fp32 + bf16 row)
    {
        GemmOp r0 = mkop(CFT, CT, p, p, p, nullptr, Rb, nullptr, R32);
        stein_gemm_nt2<<<g1, blk, 0, stream>>>(r0, r0);
    }

    u16* Tb[2]  = {AFT, Tb1};
    u16* TbT[2] = {AFb, TbT1};
    u16* Ub[2]  = {Ab, Ub1};
    u16* UbT[2] = {AT, UbT1};

    for (int i = 0; i < 6; ++i) {
        const int c = i & 1, nx = c ^ 1;
        GemmOp oXT = mkop(Rb, UbT[c], n, n, n, nullptr, nullptr, XT, nullptr);
        if (i < 5) {
            GemmOp oBsq = mkop(Tb[c], TbT[c], n, n, n, nullptr, Tb[nx], TbT[nx], nullptr);
            stein_gemm_nt2<<<g2, blk, 0, stream>>>(oXT, oBsq);
            GemmOp oRup = mkop(Tb[c], XT, n, n, n, R32, Rb, nullptr, R32);
            GemmOp oAsq = mkop(Ub[c], UbT[c], n, n, n, nullptr, Ub[nx], UbT[nx], nullptr);
            stein_gemm_nt2<<<g2, blk, 0, stream>>>(oRup, oAsq);
        } else {
            stein_gemm_nt2<<<g1, blk, 0, stream>>>(oXT, oXT);
            // final: S_64 = B_5 X + R -> fp32 d_out
            GemmOp oFin = mkop(Tb[c], XT, n, n, n, R32, nullptr, nullptr, (float*)d_out);
            stein_gemm_nt2<<<g1, blk, 0, stream>>>(oFin, oFin);
        }
    }
}

// Round 10
// 649.914 us; speedup vs baseline: 3.2798x; 1.0186x over previous
//
#include <hip/hip_runtime.h>
#include <hip/hip_bf16.h>
#include <stdint.h>

typedef __attribute__((ext_vector_type(4))) float f32x4;
typedef __attribute__((ext_vector_type(8))) short s16x8;
typedef unsigned short u16;

#define BM 128
#define BN 128
#define BK 64

// round-to-nearest-even f32 -> bf16 (bit pattern)
__device__ __forceinline__ u16 f32_to_bf16(float f) {
    uint32_t u = __float_as_uint(f);
    u = u + 0x7FFFu + ((u >> 16) & 1u);
    return (u16)(u >> 16);
}

__device__ __forceinline__ void gld_lds16(const void* g, void* l) {
    __builtin_amdgcn_global_load_lds(
        (const __attribute__((address_space(1))) uint32_t*)g,
        (__attribute__((address_space(3))) uint32_t*)l,
        16, 0, 0);
}

// Transpose + convert: out[c*R + r] = bf16(in[r*C + c]).  R, C multiples of 32.
__global__ void stein_transpose_f32_bf16(const float* __restrict__ in,
                                         u16* __restrict__ out, int R, int C) {
    __shared__ float tile[32][33];
    const int tx = threadIdx.x, ty = threadIdx.y;     // 32 x 8
    const int c0 = blockIdx.x * 32, r0 = blockIdx.y * 32;
#pragma unroll
    for (int i = 0; i < 32; i += 8)
        tile[ty + i][tx] = in[(size_t)(r0 + ty + i) * C + (c0 + tx)];
    __syncthreads();
#pragma unroll
    for (int i = 0; i < 32; i += 8)
        out[(size_t)(c0 + ty + i) * R + (r0 + tx)] = f32_to_bf16(tile[tx][ty + i]);
}

// Straight convert f32 -> bf16, 4 elements/thread. n multiple of 4.
__global__ void stein_convert_f32_bf16(const float* __restrict__ in,
                                       u16* __restrict__ out, int n) {
    int i = (blockIdx.x * blockDim.x + threadIdx.x) * 4;
    if (i >= n) return;
    f32x4 v = *(const f32x4*)(in + i);
    uint2 u;
    u.x = (uint32_t)f32_to_bf16(v[0]) | ((uint32_t)f32_to_bf16(v[1]) << 16);
    u.y = (uint32_t)f32_to_bf16(v[2]) | ((uint32_t)f32_to_bf16(v[3]) << 16);
    *(uint2*)(out + i) = u;
}

// Runtime-descriptor GEMM op: C[m,n] = sum_k U[m,k] V[n,k]  (NT, bf16 in).
struct GemmOp {
    const u16* U; const u16* V;
    const float* Add;
    u16* OutB; u16* OutT; float* OutF;
    int K, ldu, ldv;
};

// grid (16,16,z) — blockIdx.z selects op0/op1. 128x128x64 tile, 4 waves,
// depth-1 double-buffered LDS via global_load_lds. See R9 notes: BK=64
// halves barrier count vs BK=32 (70 -> 58.8 µs paired); LDS 64 KB/block
// keeps 2 blocks/CU. R10: ops are PAIRED to share one input stream
// (d1 shares V = A_i^T, d2 shares U = B_i) — blocks of op0/op1 with the
// same (bm,bn) stream identical slabs, halving L2 pressure per dispatch.
// Bank swizzle (0 conflicts measured): physical chunk p of row r holds
// logical chunk p ^ (r&7); readers use (s*4+(lane>>4)) ^ (lane&7).
__global__ __launch_bounds__(256, 2) void stein_gemm_nt2(GemmOp op0, GemmOp op1) {
    const GemmOp op = (blockIdx.z == 0) ? op0 : op1;
    __shared__ alignas(16) short Us[2][BM * BK];   // 2 x 16 KB
    __shared__ alignas(16) short Vs[2][BN * BK];   // 2 x 16 KB

    const int t = threadIdx.x;
    const int wave = t >> 6;
    const int lane = t & 63;
    const int bm = blockIdx.x, bn = blockIdx.y;
    const int wm = (wave >> 1) * 64;
    const int wn = (wave & 1) * 64;

    // staging: wave w covers rows [32w, 32w+32) of U and V; 4 DMA ops each
    // (8 rows x 128 B per op).
    const int lrow8 = lane >> 3;                  // 0..7
    const int lchunk = (lane & 7) ^ lrow8;        // swizzled source chunk
    const u16* gU = op.U + (size_t)(bm * BM + wave * 32 + lrow8) * op.ldu + lchunk * 8;
    const u16* gV = op.V + (size_t)(bn * BN + wave * 32 + lrow8) * op.ldv + lchunk * 8;
    short* sU = &Us[0][(wave * 32) * BK];
    short* sV = &Vs[0][(wave * 32) * BK];
    const int bufU = BM * BK;                     // elements per buffer
    const int bufV = BN * BK;

    f32x4 acc[4][4];
#pragma unroll
    for (int i = 0; i < 4; ++i)
#pragma unroll
        for (int j = 0; j < 4; ++j) acc[i][j] = (f32x4){0.f, 0.f, 0.f, 0.f};

    const int arow = wm + (lane & 15);
    const int brow = wn + (lane & 15);

    // prologue: stage tile 0 into buffer 0
#pragma unroll
    for (int j = 0; j < 4; ++j) {
        gld_lds16(gU + (size_t)(8 * j) * op.ldu, sU + j * 512);
        gld_lds16(gV + (size_t)(8 * j) * op.ldv, sV + j * 512);
    }

    int buf = 0;
    for (int kk = 0; kk < op.K; kk += BK) {
        __syncthreads();   // buffer `buf` staged; prior reads of buf^1 done
        if (kk + BK < op.K) {
            const int kn = kk + BK;
            const int bo = buf ^ 1;
#pragma unroll
            for (int j = 0; j < 4; ++j) {
                gld_lds16(gU + (size_t)(8 * j) * op.ldu + kn, sU + bo * bufU + j * 512);
                gld_lds16(gV + (size_t)(8 * j) * op.ldv + kn, sV + bo * bufV + j * 512);
            }
        }
#pragma unroll
        for (int s = 0; s < 2; ++s) {
            const int cx = (s * 4 + (lane >> 4)) ^ (lane & 7);   // phys chunk
            s16x8 af[4], bfr[4];
#pragma unroll
            for (int i = 0; i < 4; ++i)
                af[i] = ((const s16x8*)Us[buf])[(arow + i * 16) * (BK / 8) + cx];
#pragma unroll
            for (int j = 0; j < 4; ++j)
                bfr[j] = ((const s16x8*)Vs[buf])[(brow + j * 16) * (BK / 8) + cx];
#pragma unroll
            for (int i = 0; i < 4; ++i)
#pragma unroll
                for (int j = 0; j < 4; ++j)
                    acc[i][j] = __builtin_amdgcn_mfma_f32_16x16x32_bf16(
                        af[i], bfr[j], acc[i][j], 0, 0, 0);
        }
        buf ^= 1;
    }

    // ---- epilogue ----  C/D layout: col=lane&15, row=(lane>>4)*4+r
    const int ldo = 2048;
    const int ccol = lane & 15;
    const int crow = (lane >> 4) * 4;
#pragma unroll
    for (int i = 0; i < 4; ++i) {
#pragma unroll
        for (int j = 0; j < 4; ++j) {
            const int gr0 = bm * BM + wm + i * 16 + crow;
            const int gc = bn * BN + wn + j * 16 + ccol;
            float v[4];
#pragma unroll
            for (int r = 0; r < 4; ++r) {
                v[r] = acc[i][j][r];
                if (op.Add) v[r] += op.Add[(size_t)(gr0 + r) * ldo + gc];
            }
            if (op.OutB) {
#pragma unroll
                for (int r = 0; r < 4; ++r)
                    op.OutB[(size_t)(gr0 + r) * ldo + gc] = f32_to_bf16(v[r]);
            }
            if (op.OutT) {
                uint2 u;
                u.x = (uint32_t)f32_to_bf16(v[0]) | ((uint32_t)f32_to_bf16(v[1]) << 16);
                u.y = (uint32_t)f32_to_bf16(v[2]) | ((uint32_t)f32_to_bf16(v[3]) << 16);
                *(uint2*)(&op.OutT[(size_t)gc * ldo + gr0]) = u;   // gr0 % 4 == 0
            }
            if (op.OutF) {
#pragma unroll
                for (int r = 0; r < 4; ++r)
                    op.OutF[(size_t)(gr0 + r) * ldo + gc] = v[r];
            }
        }
    }
}

static inline GemmOp mkop(const u16* U, const u16* V, int K, int ldu, int ldv,
                          const float* Add, u16* OutB, u16* OutT, float* OutF) {
    GemmOp o;
    o.U = U; o.V = V; o.Add = Add; o.OutB = OutB; o.OutT = OutT; o.OutF = OutF;
    o.K = K; o.ldu = ldu; o.ldv = ldv;
    return o;
}

extern "C" void kernel_launch(void* const* d_in, const int* in_sizes, int n_in,
                              void* d_out, int out_size, void* d_ws, size_t ws_size,
                              hipStream_t stream) {
    const float* A = (const float*)d_in[0];     // (2048, 2048)
    const float* A_F = (const float*)d_in[1];   // (2048, 2048)
    const float* C = (const float*)d_in[2];     // (512, 2048)
    const float* C_F = (const float*)d_in[3];   // (512, 2048)
    const int n = 2048, p = 512;
    (void)in_sizes; (void)n_in; (void)out_size; (void)ws_size;

    char* ws = (char*)d_ws;
    const size_t MB = 1u << 20;
    // ---- Smith squaring, 6 levels -> S_64 (measured absmax 0.5; S_32 tail
    // ~1.5 absmax — too close to the 2.33 threshold, stay at 6).
    u16* AT   = (u16*)(ws + 0 * MB);    // A^T  bf16  (A_0 transposed form)
    u16* Ab   = (u16*)(ws + 8 * MB);    // A    bf16  (A_0 row form)
    u16* AFT  = (u16*)(ws + 16 * MB);   // B=A_F^T row bf16 (B_0 row form)
    u16* AFb  = (u16*)(ws + 24 * MB);   // A_F  bf16  (B_0 transposed form)
    u16* CFT  = (u16*)(ws + 32 * MB);   // C_F^T bf16 (2048x512)
    u16* CT   = (u16*)(ws + 34 * MB);   // C^T   bf16 (2048x512)
    float* R32 = (float*)(ws + 36 * MB);// running R fp32
    u16* Rb   = (u16*)(ws + 52 * MB);   // running R bf16 row
    u16* XT   = (u16*)(ws + 60 * MB);   // (R*A_i)^T bf16
    u16* Tb1  = (u16*)(ws + 68 * MB);   // ping-pong set 1: B_i row
    u16* TbT1 = (u16*)(ws + 76 * MB);   //                  B_i^T
    u16* Ub1  = (u16*)(ws + 84 * MB);   //                  A_i row
    u16* UbT1 = (u16*)(ws + 92 * MB);   //                  A_i^T

    dim3 tb(32, 8);
    stein_transpose_f32_bf16<<<dim3(64, 64), tb, 0, stream>>>(A, AT, n, n);
    stein_convert_f32_bf16<<<4096, 256, 0, stream>>>(A, Ab, n * n);
    stein_transpose_f32_bf16<<<dim3(64, 64), tb, 0, stream>>>(A_F, AFT, n, n);
    stein_convert_f32_bf16<<<4096, 256, 0, stream>>>(A_F, AFb, n * n);
    stein_transpose_f32_bf16<<<dim3(64, 16), tb, 0, stream>>>(C_F, CFT, p, n);
    stein_transpose_f32_bf16<<<dim3(64, 16), tb, 0, stream>>>(C, CT, p, n);

    dim3 blk(256);
    dim3 g1(16, 16, 1), g2(16, 16, 2);
    // R_0 = C_F^T C  (fp32 + bf16 row)
    {
        GemmOp r0 = mkop(CFT, CT, p, p, p, nullptr, Rb, nullptr, R32);
        stein_gemm_nt2<<<g1, blk, 0, stream>>>(r0, r0);
    }

    u16* Tb[2]  = {AFT, Tb1};
    u16* TbT[2] = {AFb, TbT1};
    u16* Ub[2]  = {Ab, Ub1};
    u16* UbT[2] = {AT, UbT1};

    for (int i = 0; i < 6; ++i) {
        const int c = i & 1, nx = c ^ 1;
        GemmOp oXT = mkop(Rb, UbT[c], n, n, n, nullptr, nullptr, XT, nullptr);
        if (i < 5) {
            // d1: {XT = R A_i, Asq = A_i^2} — SHARED V stream = A_i^T.
            GemmOp oAsq = mkop(Ub[c], UbT[c], n, n, n, nullptr, Ub[nx], UbT[nx], nullptr);
            stein_gemm_nt2<<<g2, blk, 0, stream>>>(oXT, oAsq);
            // d2: {Rup = B_i X + R, Bsq = B_i^2} — SHARED U stream = B_i.
            GemmOp oRup = mkop(Tb[c], XT, n, n, n, R32, Rb, nullptr, R32);
            GemmOp oBsq = mkop(Tb[c], TbT[c], n, n, n, nullptr, Tb[nx], TbT[nx], nullptr);
            stein_gemm_nt2<<<g2, blk, 0, stream>>>(oRup, oBsq);
        } else {
            stein_gemm_nt2<<<g1, blk, 0, stream>>>(oXT, oXT);
            // final: S_64 = B_5 X + R -> fp32 d_out
            GemmOp oFin = mkop(Tb[c], XT, n, n, n, R32, nullptr, nullptr, (float*)d_out);
            stein_gemm_nt2<<<g1, blk, 0, stream>>>(oFin, oFin);
        }
    }
}